// Round 6
// baseline (367.244 us; speedup 1.0000x reference)
//
#include <hip/hip_runtime.h>
#include <math.h>

// GammaContrastReconLoss: total = 0.5*supcon + 0.5*masked_mse
// B=2048, D=1024, S=128, H=512. Assumes B%128==0, D%64==0, (H/4) pow2.
//
// norm_convert (also zero-inits ws header) -> FUSED{contrast MFMA tiles
// [contiguous bids 0..NC — NEVER stripe roles with period sharing a factor
// with 8: bid%8 picks the XCD, R5 regression] | recon stream | masksum |
// last-block finalize}. Contrast branch sized for low natural VGPR
// (acc[4][2]+b[2]+a ~ 100) so no launch-bounds cap (R4: cap => K-loop spills).

#define TEMP_INV 10.0f   // 1/TEMP
#define GAMMA 0.5f

using short8 = __attribute__((ext_vector_type(8))) short;  // 8 bf16 (4 VGPRs)
using f32x4  = __attribute__((ext_vector_type(4))) float;  // MFMA acc / vec load

__device__ __forceinline__ float blockReduceSum(float v) {
    __shared__ float red[8];
    #pragma unroll
    for (int off = 32; off > 0; off >>= 1) v += __shfl_down(v, off, 64);
    int lane = threadIdx.x & 63, wid = threadIdx.x >> 6;
    __syncthreads();
    if (lane == 0) red[wid] = v;
    __syncthreads();
    float r = 0.f;
    if (threadIdx.x == 0) {
        int nw = (blockDim.x + 63) >> 6;
        for (int w = 0; w < nw; ++w) r += red[w];
    }
    return r;  // valid in thread 0 only
}

__device__ __forceinline__ unsigned short f2bf(float f) {  // RNE f32->bf16 bits
    unsigned u = __float_as_uint(f);
    unsigned r = (u + 0x7FFFu + ((u >> 16) & 1u)) >> 16;
    return (unsigned short)r;
}

// ---- 1. row-normalize latents -> bf16; also zero-init ws header ---------
__global__ void norm_convert_kernel(const float* __restrict__ x,
                                    unsigned short* __restrict__ nbf,
                                    float* __restrict__ denomAcc,
                                    float* __restrict__ posAcc,
                                    float* __restrict__ cntAcc,
                                    float* __restrict__ racc,
                                    float* __restrict__ msum,
                                    unsigned* __restrict__ doneCnt, int D) {
    int row = blockIdx.x;
    if (threadIdx.x == 0) {                 // zero this row's accumulators
        denomAcc[row] = 0.f; posAcc[row] = 0.f; cntAcc[row] = 0.f;
        if (row == 0) { racc[0] = 0.f; msum[0] = 0.f; doneCnt[0] = 0u; }
    }
    const float4* xr = (const float4*)(x + (size_t)row * D);
    unsigned short* nr = nbf + (size_t)row * D;
    int n4 = D >> 2;
    float s = 0.f;
    for (int i = threadIdx.x; i < n4; i += blockDim.x) {
        float4 v = xr[i];
        s += v.x * v.x + v.y * v.y + v.z * v.z + v.w * v.w;
    }
    float tot = blockReduceSum(s);
    __shared__ float s_inv;
    if (threadIdx.x == 0) s_inv = 1.0f / fmaxf(sqrtf(tot), 1e-12f);
    __syncthreads();
    float inv = s_inv;
    for (int i = threadIdx.x; i < n4; i += blockDim.x) {
        float4 v = xr[i];
        ushort4 o;
        o.x = f2bf(v.x * inv); o.y = f2bf(v.y * inv);
        o.z = f2bf(v.z * inv); o.w = f2bf(v.w * inv);
        *(ushort4*)(nr + i * 4) = o;
    }
}

// ---- 2. FUSED: contrast MFMA | recon stream | masksum | finalize --------
// bid < NC           : contrast tile (contiguous -> spreads over all XCDs)
// NC <= bid < NC+NR  : recon masked-MSE grid-stride stream
// else               : mask sum
__launch_bounds__(256)
__global__ void fused_kernel(const short* __restrict__ nbf,
                             const int* __restrict__ labels,
                             const f32x4* __restrict__ p4,
                             const f32x4* __restrict__ t4,
                             const float* __restrict__ mask,
                             float* __restrict__ denomAcc,
                             float* __restrict__ posAcc,
                             float* __restrict__ cntAcc,
                             float* __restrict__ racc,
                             float* __restrict__ msum,
                             unsigned* __restrict__ doneCnt,
                             float* __restrict__ out,
                             int B, int D, float invH,
                             unsigned n4, int shiftH4, unsigned nBS4,
                             int nbxc, int NC, int NR) {
    constexpr int BM = 128, BN = 64, BK = 64;
    __shared__ short As[BM * BK];           // 16 KB
    __shared__ short Bs[BN * BK];           //  8 KB

    const int tid = threadIdx.x;
    const int bid = blockIdx.x;

    if (bid < NC) {
        // ---------------- contrast tile (128x64) ----------------
        const int lane = tid & 63;
        const int w    = tid >> 6;
        const int wr   = w >> 1, wc = w & 1;        // 2x2 waves, wave tile 64x32
        const int brow = (bid / nbxc) * BM;
        const int bcol = (bid % nbxc) * BN;
        const int g    = lane >> 4, l15 = lane & 15;

        f32x4 acc[4][2] = {};

        for (int k0 = 0; k0 < D; k0 += BK) {
            // stage tiles; write-side swizzle: 16B unit ^= (row&7)
            #pragma unroll
            for (int i = 0; i < 4; ++i) {           // A: 1024 chunks
                int chunk = i * 256 + tid;
                int r = chunk >> 3, cu = chunk & 7;
                int su = cu ^ (r & 7);
                uint4 va = *(const uint4*)(nbf + (size_t)(brow + r) * D + k0 + cu * 8);
                *(uint4*)(As + r * BK + su * 8) = va;
            }
            #pragma unroll
            for (int i = 0; i < 2; ++i) {           // B: 512 chunks
                int chunk = i * 256 + tid;
                int r = chunk >> 3, cu = chunk & 7;
                int su = cu ^ (r & 7);
                uint4 vb = *(const uint4*)(nbf + (size_t)(bcol + r) * D + k0 + cu * 8);
                *(uint4*)(Bs + r * BK + su * 8) = vb;
            }
            __syncthreads();

            #pragma unroll
            for (int ks = 0; ks < 2; ++ks) {
                short8 b[2];
                #pragma unroll
                for (int ni = 0; ni < 2; ++ni) {
                    int rb = wc * 32 + ni * 16 + l15;
                    int ub = (ks * 4 + g) ^ (rb & 7);
                    b[ni] = *(const short8*)(Bs + rb * BK + ub * 8);
                }
                #pragma unroll
                for (int mi = 0; mi < 4; ++mi) {
                    int ra = wr * 64 + mi * 16 + l15;
                    int ua = (ks * 4 + g) ^ (ra & 7);
                    short8 a = *(const short8*)(As + ra * BK + ua * 8);
                    #pragma unroll
                    for (int ni = 0; ni < 2; ++ni)
                        acc[mi][ni] = __builtin_amdgcn_mfma_f32_16x16x32_bf16(
                            a, b[ni], acc[mi][ni], 0, 0, 0);
                }
            }
            __syncthreads();
        }

        // epilogue: sim = cos * 10; fused per-row reductions
        int lc[2], gcv[2];
        #pragma unroll
        for (int ni = 0; ni < 2; ++ni) {
            gcv[ni] = bcol + wc * 32 + ni * 16 + l15;
            lc[ni]  = labels[gcv[ni]];
        }
        #pragma unroll
        for (int mi = 0; mi < 4; ++mi) {
            #pragma unroll
            for (int r = 0; r < 4; ++r) {
                int R  = brow + wr * 64 + mi * 16 + g * 4 + r;
                int lr = labels[R];
                float d = 0.f, p = 0.f, c = 0.f;
                #pragma unroll
                for (int ni = 0; ni < 2; ++ni) {
                    float sim = acc[mi][ni][r] * TEMP_INV;
                    if (R != gcv[ni]) {
                        d += __expf(sim - TEMP_INV);     // exp(sim-10), sim<=10
                        if (lr == lc[ni]) { p += sim; c += 1.f; }
                    }
                }
                #pragma unroll
                for (int off = 8; off > 0; off >>= 1) {
                    d += __shfl_down(d, off, 16);
                    p += __shfl_down(p, off, 16);
                    c += __shfl_down(c, off, 16);
                }
                if (l15 == 0) {
                    atomicAdd(&denomAcc[R], d);
                    atomicAdd(&posAcc[R], p);
                    atomicAdd(&cntAcc[R], c);
                }
            }
        }
    } else if (bid < NC + NR) {
        // ---------------- recon stream (x2 unrolled) ----------------
        int rid = bid - NC;
        unsigned stride = (unsigned)NR * blockDim.x;
        unsigned i = (unsigned)rid * blockDim.x + tid;
        float local = 0.f;
        for (; i + stride < n4; i += 2 * stride) {
            f32x4 a0 = __builtin_nontemporal_load(&p4[i]);
            f32x4 b0 = __builtin_nontemporal_load(&t4[i]);
            f32x4 a1 = __builtin_nontemporal_load(&p4[i + stride]);
            f32x4 b1 = __builtin_nontemporal_load(&t4[i + stride]);
            float m0 = mask[i >> shiftH4];
            float m1 = mask[(i + stride) >> shiftH4];
            f32x4 d0 = a0 - b0, d1 = a1 - b1;
            local += m0 * (d0[0]*d0[0] + d0[1]*d0[1] + d0[2]*d0[2] + d0[3]*d0[3]);
            local += m1 * (d1[0]*d1[0] + d1[1]*d1[1] + d1[2]*d1[2] + d1[3]*d1[3]);
        }
        if (i < n4) {
            f32x4 a0 = __builtin_nontemporal_load(&p4[i]);
            f32x4 b0 = __builtin_nontemporal_load(&t4[i]);
            float m0 = mask[i >> shiftH4];
            f32x4 d0 = a0 - b0;
            local += m0 * (d0[0]*d0[0] + d0[1]*d0[1] + d0[2]*d0[2] + d0[3]*d0[3]);
        }
        float tot = blockReduceSum(local);
        if (tid == 0) atomicAdd(racc, tot);
    } else {
        // ---------------- mask sum ----------------
        int nm = gridDim.x - NC - NR;
        unsigned i = (unsigned)(bid - NC - NR) * blockDim.x + tid;
        unsigned stride = (unsigned)nm * blockDim.x;
        float local = 0.f;
        for (; i < nBS4; i += stride) {
            f32x4 m = *(const f32x4*)(mask + 4 * (size_t)i);
            local += m[0] + m[1] + m[2] + m[3];
        }
        float tot = blockReduceSum(local);
        if (tid == 0) atomicAdd(msum, tot);
    }

    // ---------------- last-block finalize ----------------
    __shared__ unsigned s_old;
    __syncthreads();                       // all role work (incl. atomics) done
    if (tid == 0) {
        __threadfence();                   // make this block's adds visible
        s_old = atomicAdd(doneCnt, 1u);
    }
    __syncthreads();
    if (s_old == gridDim.x - 1) {
        __threadfence();                   // order after counter observation
        float lsum = 0.f, vcnt = 0.f;
        for (int r = tid; r < B; r += blockDim.x) {
            float c = __hip_atomic_load(&cntAcc[r], __ATOMIC_RELAXED, __HIP_MEMORY_SCOPE_AGENT);
            if (c > 0.5f) {
                float dn = __hip_atomic_load(&denomAcc[r], __ATOMIC_RELAXED, __HIP_MEMORY_SCOPE_AGENT);
                float ps = __hip_atomic_load(&posAcc[r], __ATOMIC_RELAXED, __HIP_MEMORY_SCOPE_AGENT);
                lsum += (logf(dn) + TEMP_INV) - ps / c;   // log(sum exp(sim-10))+10
                vcnt += 1.f;
            }
        }
        lsum = blockReduceSum(lsum);
        vcnt = blockReduceSum(vcnt);
        if (tid == 0) {
            float ra = __hip_atomic_load(racc, __ATOMIC_RELAXED, __HIP_MEMORY_SCOPE_AGENT);
            float ms = __hip_atomic_load(msum, __ATOMIC_RELAXED, __HIP_MEMORY_SCOPE_AGENT);
            float contrast = lsum / fmaxf(vcnt, 1.f);
            float recon = ra * invH / fmaxf(ms, 1.f);
            out[0] = GAMMA * contrast + (1.f - GAMMA) * recon;
            out[1] = contrast;
            out[2] = recon;
        }
    }
}

extern "C" void kernel_launch(void* const* d_in, const int* in_sizes, int n_in,
                              void* d_out, int out_size, void* d_ws, size_t ws_size,
                              hipStream_t stream) {
    const float* latents = (const float*)d_in[0];
    const float* recon   = (const float*)d_in[1];
    const float* target  = (const float*)d_in[2];
    const float* mask    = (const float*)d_in[3];
    const int*   labels  = (const int*)d_in[4];
    float* out = (float*)d_out;
    float* ws  = (float*)d_ws;

    int B = in_sizes[4];
    int D = in_sizes[0] / B;
    int S = in_sizes[3] / B;
    int H = (in_sizes[1] / B) / S;

    // ws floats: denom[B] | pos[B] | cnt[B] | racc | msum | doneCnt | pad.. | nbf
    float* denom = ws;
    float* pos   = ws + B;
    float* cnt   = ws + 2 * B;
    float* racc  = ws + 3 * B;
    float* msum  = ws + 3 * B + 1;
    unsigned* doneCnt = (unsigned*)(ws + 3 * B + 2);
    unsigned short* nbf = (unsigned short*)(ws + 3 * B + 64);  // 16B-aligned

    norm_convert_kernel<<<B, 256, 0, stream>>>(latents, nbf, denom, pos, cnt,
                                               racc, msum, doneCnt, D);

    int nbxc = B / 64;                 // 32 col tiles (BN=64)
    int NC = (B / 128) * nbxc;         // 512 contrast tiles, contiguous bids
    int NR = 3072;                     // recon stream blocks (small, self-balancing)
    int NM = 32;                       // masksum blocks
    unsigned n4 = (unsigned)B * (unsigned)S * (unsigned)(H / 4);
    unsigned nBS4 = (unsigned)(B * S) / 4;
    int shiftH4 = __builtin_ctz((unsigned)(H / 4));

    fused_kernel<<<NC + NR + NM, 256, 0, stream>>>(
        (const short*)nbf, labels, (const f32x4*)recon, (const f32x4*)target,
        mask, denom, pos, cnt, racc, msum, doneCnt, out,
        B, D, 1.0f / H, n4, shiftH4, nBS4, nbxc, NC, NR);
}

// Round 7
// 197.256 us; speedup vs baseline: 1.8618x; 1.8618x over previous
//
#include <hip/hip_runtime.h>
#include <math.h>

// GammaContrastReconLoss: total = 0.5*supcon + 0.5*masked_mse
// B=2048, D=1024, S=128, H=512. Assumes B%128==0, D%64==0, (H/4) pow2.
//
// R3-champion structure: norm_convert (+ws-header zero-init) ->
// FUSED{contrast MFMA tiles (contiguous bids) | recon stream | masksum} ->
// separate finalize kernel.
// HARD-LEARNED: NO per-block __threadfence/last-block finalize (agent fence
// = per-XCD L2 writeback+invalidate; cost scales with grid size: R4-R6
// regressions 270/300/367 us vs this structure's 228). No launch_bounds
// min-wave cap (R4: K-loop spills). No role striping by bid%4 (R5: XCD skew).

#define TEMP_INV 10.0f   // 1/TEMP
#define GAMMA 0.5f

using short8 = __attribute__((ext_vector_type(8))) short;  // 8 bf16 (4 VGPRs)
using f32x4  = __attribute__((ext_vector_type(4))) float;  // MFMA acc / vec load

__device__ __forceinline__ float blockReduceSum(float v) {
    __shared__ float red[8];
    #pragma unroll
    for (int off = 32; off > 0; off >>= 1) v += __shfl_down(v, off, 64);
    int lane = threadIdx.x & 63, wid = threadIdx.x >> 6;
    __syncthreads();
    if (lane == 0) red[wid] = v;
    __syncthreads();
    float r = 0.f;
    if (threadIdx.x == 0) {
        int nw = (blockDim.x + 63) >> 6;
        for (int w = 0; w < nw; ++w) r += red[w];
    }
    return r;  // valid in thread 0 only
}

__device__ __forceinline__ unsigned short f2bf(float f) {  // RNE f32->bf16 bits
    unsigned u = __float_as_uint(f);
    unsigned r = (u + 0x7FFFu + ((u >> 16) & 1u)) >> 16;
    return (unsigned short)r;
}

// ---- 1. row-normalize latents -> bf16; also zero-init ws header ---------
__global__ void norm_convert_kernel(const float* __restrict__ x,
                                    unsigned short* __restrict__ nbf,
                                    float* __restrict__ denomAcc,
                                    float* __restrict__ posAcc,
                                    float* __restrict__ cntAcc,
                                    float* __restrict__ racc,
                                    float* __restrict__ msum, int D) {
    int row = blockIdx.x;
    if (threadIdx.x == 0) {                 // zero this row's accumulators
        denomAcc[row] = 0.f; posAcc[row] = 0.f; cntAcc[row] = 0.f;
        if (row == 0) { racc[0] = 0.f; msum[0] = 0.f; }
    }
    const float4* xr = (const float4*)(x + (size_t)row * D);
    unsigned short* nr = nbf + (size_t)row * D;
    int n4 = D >> 2;
    float s = 0.f;
    for (int i = threadIdx.x; i < n4; i += blockDim.x) {
        float4 v = xr[i];
        s += v.x * v.x + v.y * v.y + v.z * v.z + v.w * v.w;
    }
    float tot = blockReduceSum(s);
    __shared__ float s_inv;
    if (threadIdx.x == 0) s_inv = 1.0f / fmaxf(sqrtf(tot), 1e-12f);
    __syncthreads();
    float inv = s_inv;
    for (int i = threadIdx.x; i < n4; i += blockDim.x) {
        float4 v = xr[i];
        ushort4 o;
        o.x = f2bf(v.x * inv); o.y = f2bf(v.y * inv);
        o.z = f2bf(v.z * inv); o.w = f2bf(v.w * inv);
        *(ushort4*)(nr + i * 4) = o;
    }
}

// ---- 2. FUSED: contrast MFMA | recon stream | masksum --------------------
// bid < NC           : contrast 128x128 tile (contiguous bids)
// NC <= bid < NC+NR  : recon masked-MSE grid-stride stream
// else               : mask sum
__launch_bounds__(256)
__global__ void fused_kernel(const short* __restrict__ nbf,
                             const int* __restrict__ labels,
                             const f32x4* __restrict__ p4,
                             const f32x4* __restrict__ t4,
                             const float* __restrict__ mask,
                             float* __restrict__ denomAcc,
                             float* __restrict__ posAcc,
                             float* __restrict__ cntAcc,
                             float* __restrict__ racc,
                             float* __restrict__ msum,
                             int B, int D,
                             unsigned n4, int shiftH4, unsigned nBS4,
                             int nbx, int NC, int NR) {
    constexpr int BM = 128, BK = 64;
    __shared__ short lds[2 * BM * BK];      // 32 KB (contrast branch only)
    short* As = lds;
    short* Bs = lds + BM * BK;

    const int tid = threadIdx.x;
    const int bid = blockIdx.x;

    if (bid < NC) {
        // ---------------- contrast tile (128x128) ----------------
        const int lane = tid & 63;
        const int w    = tid >> 6;
        const int wr   = w >> 1, wc = w & 1;
        const int brow = (bid / nbx) * BM;
        const int bcol = (bid % nbx) * BM;
        const int g    = lane >> 4, l15 = lane & 15;

        f32x4 acc[4][4] = {};

        for (int k0 = 0; k0 < D; k0 += BK) {
            // stage 128x64 bf16 tiles; write-side swizzle: 16B unit ^= (row&7)
            #pragma unroll
            for (int i = 0; i < 4; ++i) {
                int chunk = i * 256 + tid;        // 0..1023
                int r  = chunk >> 3;              // 0..127
                int cu = chunk & 7;               // 16B unit in row
                int su = cu ^ (r & 7);
                uint4 va = *(const uint4*)(nbf + (size_t)(brow + r) * D + k0 + cu * 8);
                *(uint4*)(As + r * BK + su * 8) = va;
                uint4 vb = *(const uint4*)(nbf + (size_t)(bcol + r) * D + k0 + cu * 8);
                *(uint4*)(Bs + r * BK + su * 8) = vb;
            }
            __syncthreads();

            // low-VGPR order: only b[4] (32 VGPR) + one a (4 VGPR) live
            #pragma unroll
            for (int ks = 0; ks < 2; ++ks) {
                short8 b[4];
                #pragma unroll
                for (int ni = 0; ni < 4; ++ni) {
                    int rb = wc * 64 + ni * 16 + l15;
                    int ub = (ks * 4 + g) ^ (rb & 7);
                    b[ni] = *(const short8*)(Bs + rb * BK + ub * 8);
                }
                #pragma unroll
                for (int mi = 0; mi < 4; ++mi) {
                    int ra = wr * 64 + mi * 16 + l15;
                    int ua = (ks * 4 + g) ^ (ra & 7);
                    short8 a = *(const short8*)(As + ra * BK + ua * 8);
                    #pragma unroll
                    for (int ni = 0; ni < 4; ++ni)
                        acc[mi][ni] = __builtin_amdgcn_mfma_f32_16x16x32_bf16(
                            a, b[ni], acc[mi][ni], 0, 0, 0);
                }
            }
            __syncthreads();
        }

        // epilogue: sim = cos * 10; fused per-row reductions
        int lc[4], gcv[4];
        #pragma unroll
        for (int ni = 0; ni < 4; ++ni) {
            gcv[ni] = bcol + wc * 64 + ni * 16 + l15;
            lc[ni]  = labels[gcv[ni]];
        }
        #pragma unroll
        for (int mi = 0; mi < 4; ++mi) {
            #pragma unroll
            for (int r = 0; r < 4; ++r) {
                int R  = brow + wr * 64 + mi * 16 + g * 4 + r;
                int lr = labels[R];
                float d = 0.f, p = 0.f, c = 0.f;
                #pragma unroll
                for (int ni = 0; ni < 4; ++ni) {
                    float sim = acc[mi][ni][r] * TEMP_INV;
                    if (R != gcv[ni]) {
                        d += __expf(sim - TEMP_INV);     // exp(sim-10), sim<=10
                        if (lr == lc[ni]) { p += sim; c += 1.f; }
                    }
                }
                #pragma unroll
                for (int off = 8; off > 0; off >>= 1) {
                    d += __shfl_down(d, off, 16);
                    p += __shfl_down(p, off, 16);
                    c += __shfl_down(c, off, 16);
                }
                if (l15 == 0) {
                    atomicAdd(&denomAcc[R], d);
                    atomicAdd(&posAcc[R], p);
                    atomicAdd(&cntAcc[R], c);
                }
            }
        }
    } else if (bid < NC + NR) {
        // ---------------- recon stream ----------------
        unsigned i = (unsigned)(bid - NC) * blockDim.x + tid;
        unsigned stride = (unsigned)NR * blockDim.x;
        float local = 0.f;
        for (; i < n4; i += stride) {
            f32x4 a = __builtin_nontemporal_load(&p4[i]);
            f32x4 b = __builtin_nontemporal_load(&t4[i]);
            float m = mask[i >> shiftH4];
            f32x4 dfl = a - b;
            local += m * (dfl[0] * dfl[0] + dfl[1] * dfl[1] +
                          dfl[2] * dfl[2] + dfl[3] * dfl[3]);
        }
        float tot = blockReduceSum(local);
        if (tid == 0) atomicAdd(racc, tot);
    } else {
        // ---------------- mask sum ----------------
        int nm = gridDim.x - NC - NR;
        unsigned i = (unsigned)(bid - NC - NR) * blockDim.x + tid;
        unsigned stride = (unsigned)nm * blockDim.x;
        float local = 0.f;
        for (; i < nBS4; i += stride) {
            f32x4 m = *(const f32x4*)(mask + 4 * (size_t)i);
            local += m[0] + m[1] + m[2] + m[3];
        }
        float tot = blockReduceSum(local);
        if (tid == 0) atomicAdd(msum, tot);
    }
}

// ---- 3. finalize ---------------------------------------------------------
__global__ void finalize_kernel(const float* __restrict__ denom, const float* __restrict__ pos,
                                const float* __restrict__ cnt, const float* __restrict__ racc,
                                const float* __restrict__ msum, float* __restrict__ out,
                                int B, float invH) {
    float lsum = 0.f, vcnt = 0.f;
    for (int r = threadIdx.x; r < B; r += blockDim.x) {
        float c = cnt[r];
        if (c > 0.5f) {
            float ld = logf(denom[r]) + TEMP_INV;     // log(sum exp(sim-10)) + 10
            lsum += ld - pos[r] / c;
            vcnt += 1.f;
        }
    }
    lsum = blockReduceSum(lsum);
    vcnt = blockReduceSum(vcnt);
    if (threadIdx.x == 0) {
        float contrast = lsum / fmaxf(vcnt, 1.f);
        float recon = racc[0] * invH / fmaxf(msum[0], 1.f);
        out[0] = GAMMA * contrast + (1.f - GAMMA) * recon;
        out[1] = contrast;
        out[2] = recon;
    }
}

extern "C" void kernel_launch(void* const* d_in, const int* in_sizes, int n_in,
                              void* d_out, int out_size, void* d_ws, size_t ws_size,
                              hipStream_t stream) {
    const float* latents = (const float*)d_in[0];
    const float* recon   = (const float*)d_in[1];
    const float* target  = (const float*)d_in[2];
    const float* mask    = (const float*)d_in[3];
    const int*   labels  = (const int*)d_in[4];
    float* out = (float*)d_out;
    float* ws  = (float*)d_ws;

    int B = in_sizes[4];
    int D = in_sizes[0] / B;
    int S = in_sizes[3] / B;
    int H = (in_sizes[1] / B) / S;

    // ws floats: denom[B] | pos[B] | cnt[B] | racc | msum | pad.. | nbf[B*D bf16]
    float* denom = ws;
    float* pos   = ws + B;
    float* cnt   = ws + 2 * B;
    float* racc  = ws + 3 * B;
    float* msum  = ws + 3 * B + 1;
    unsigned short* nbf = (unsigned short*)(ws + 3 * B + 64);  // 16B-aligned

    norm_convert_kernel<<<B, 256, 0, stream>>>(latents, nbf, denom, pos, cnt,
                                               racc, msum, D);

    int nbx = B / 128;
    int NC = nbx * nbx;              // 256 contrast tiles, contiguous bids
    int NR = 1536;                   // recon stream blocks
    int NM = 16;                     // masksum blocks
    unsigned n4 = (unsigned)B * (unsigned)S * (unsigned)(H / 4);
    unsigned nBS4 = (unsigned)(B * S) / 4;
    int shiftH4 = __builtin_ctz((unsigned)(H / 4));

    fused_kernel<<<NC + NR + NM, 256, 0, stream>>>(
        (const short*)nbf, labels, (const f32x4*)recon, (const f32x4*)target,
        mask, denom, pos, cnt, racc, msum,
        B, D, n4, shiftH4, nBS4, nbx, NC, NR);

    finalize_kernel<<<1, 256, 0, stream>>>(denom, pos, cnt, racc, msum, out, B, 1.0f / H);
}